// Round 11
// baseline (512.579 us; speedup 1.0000x reference)
//
#include <hip/hip_runtime.h>

#define H 768
#define F 3072
#define NE 8
#define T 4096
#define NA 8192      // T * K assignments
#define TP 9216      // padded slot capacity (128-aligned per expert)
#define NRB 72       // max 128-row blocks

typedef unsigned short ushort_t;
typedef __attribute__((ext_vector_type(8))) short bfx8;
typedef __attribute__((ext_vector_type(4))) float fx4;
typedef __attribute__((address_space(3))) const ushort_t lus;

__device__ __forceinline__ ushort_t f2bf(float f) {
    union { float f; unsigned u; } v; v.f = f;
    unsigned u = v.u;
    unsigned r = (u + 0x7fffu + ((u >> 16) & 1u)) >> 16;
    return (ushort_t)r;
}

__device__ __forceinline__ float gelu_tanh(float x) {
    const float c = 0.7978845608028654f;
    float z = c * (x + 0.044715f * x * x * x);
    float t = 1.0f - 2.0f / (__expf(2.0f * z) + 1.0f);   // tanh(z)
    return 0.5f * x * (1.0f + t);
}

__device__ __forceinline__ void g2l16(const void* g, void* l) {
    __builtin_amdgcn_global_load_lds(
        (__attribute__((address_space(1))) void*)g,
        (__attribute__((address_space(3))) void*)l, 16, 0, 0);
}

__device__ __forceinline__ bfx8 dsr128(lus* p) {
    bfx8 r;
    asm volatile("ds_read_b128 %0, %1" : "=v"(r) : "v"(p));
    return r;
}

#define WAITV0 asm volatile("s_waitcnt vmcnt(0)" ::: "memory")
#define LGKM0  asm volatile("s_waitcnt lgkmcnt(0)" ::: "memory")
#define SBAR   asm volatile("s_barrier" ::: "memory")
#define SCHED0 __builtin_amdgcn_sched_barrier(0)
#define PRIO1  __builtin_amdgcn_s_setprio(1)
#define PRIO0  __builtin_amdgcn_s_setprio(0)

// ---------------- router: one wave per token ----------------
__global__ void router_k(const float* __restrict__ x, const float* __restrict__ gw,
                         int* __restrict__ tidx, float* __restrict__ twgt) {
    int t = blockIdx.x * 4 + (threadIdx.x >> 6);
    int lane = threadIdx.x & 63;
    const float* xr = x + (size_t)t * H;
    float acc[NE];
#pragma unroll
    for (int e = 0; e < NE; ++e) acc[e] = 0.f;
    for (int h = lane; h < H; h += 64) {
        float xv = xr[h];
        const float* g = gw + h * NE;
#pragma unroll
        for (int e = 0; e < NE; ++e) acc[e] += xv * g[e];
    }
#pragma unroll
    for (int off = 32; off > 0; off >>= 1) {
#pragma unroll
        for (int e = 0; e < NE; ++e) acc[e] += __shfl_down(acc[e], off);
    }
    if (lane == 0) {
        float l0 = -1e30f, l1 = -1e30f; int i0 = 0, i1 = 0;
#pragma unroll
        for (int e = 0; e < NE; ++e) {
            float v = acc[e];
            if (v > l0) { l1 = l0; i1 = i0; l0 = v; i0 = e; }
            else if (v > l1) { l1 = v; i1 = e; }
        }
        float w0 = 1.f / (1.f + __expf(l1 - l0));
        tidx[t * 2] = i0; tidx[t * 2 + 1] = i1;
        twgt[t * 2] = w0; twgt[t * 2 + 1] = 1.f - w0;
    }
}

__global__ void init_k(int* counts, int* tos) {
    int i = blockIdx.x * 256 + threadIdx.x;
    if (i < NE) counts[i] = 0;
    if (i < TP) tos[i] = -1;
}

__global__ void count_k(const int* __restrict__ tidx, int* counts) {
    int i = blockIdx.x * 256 + threadIdx.x;
    if (i < NA) atomicAdd(&counts[tidx[i]], 1);
}

__global__ void offsets_k(const int* __restrict__ counts, int* cursor,
                          int* rbe, int* rbs) {
    int off = 0, rb = 0;
    for (int e = 0; e < NE; ++e) {
        cursor[e] = off;
        int nrb = (counts[e] + 127) / 128;
        for (int j = 0; j < nrb; ++j) { rbe[rb] = e; rbs[rb] = off + j * 128; ++rb; }
        off += nrb * 128;
    }
    for (; rb < NRB; ++rb) rbe[rb] = -1;
}

__global__ void scatter_k(const int* __restrict__ tidx, int* cursor,
                          int* __restrict__ tos, int* __restrict__ aslot) {
    int i = blockIdx.x * 256 + threadIdx.x;
    if (i < NA) {
        int e = tidx[i];
        int slot = atomicAdd(&cursor[e], 1);
        tos[slot] = i >> 1;
        aslot[i] = slot;
    }
}

// gather selected token rows -> bf16, zeros for padding slots
__global__ void gather_k(const float* __restrict__ x, const int* __restrict__ tos,
                         ushort_t* __restrict__ xg) {
    int i = blockIdx.x * 256 + threadIdx.x;    // TP * (H/8)
    int slot = i / (H / 8);
    int j = i % (H / 8);
    int tok = tos[slot];
    ushort_t v[8];
    if (tok < 0) {
#pragma unroll
        for (int q = 0; q < 8; ++q) v[q] = 0;
    } else {
        const float* src = x + (size_t)tok * H + j * 8;
#pragma unroll
        for (int q = 0; q < 8; ++q) v[q] = f2bf(src[q]);
    }
    *(bfx8*)&xg[(size_t)slot * H + j * 8] = *(const bfx8*)v;
}

// fp32 [R][C] -> bf16 [C][R], per expert (blockIdx.z)
__global__ void transpose_cast_k(const float* __restrict__ src, ushort_t* __restrict__ dst,
                                 int R, int C) {
    int e = blockIdx.z;
    src += (size_t)e * R * C;
    dst += (size_t)e * R * C;
    int c0 = blockIdx.x * 64, r0 = blockIdx.y * 64;
    __shared__ float tile[64][65];
    int tid = threadIdx.x;
    int cc = tid & 63, rr = tid >> 6;    // rr 0..3
#pragma unroll
    for (int rep = 0; rep < 16; ++rep) {
        int r = rep * 4 + rr;
        tile[r][cc] = src[(size_t)(r0 + r) * C + c0 + cc];
    }
    __syncthreads();
#pragma unroll
    for (int rep = 0; rep < 16; ++rep) {
        int c = rep * 4 + rr;
        dst[(size_t)(c0 + c) * R + r0 + cc] = f2bf(tile[cc][c]);
    }
}

// == 128x128 x BK64 GEMM, 4 waves (64x64), A-direct-from-global, B in LDS ==
// R11: LDS-port relief. R8/R9/R10 all converged to ~45 B/cyc LDS traffic —
// the LDS port is the binding resource. A (the redundantly-read operand)
// moves to direct global->VGPR fragment loads (16B contiguous per lane;
// A panels are L2-resident via rb-major XCD chunking). Only B is staged:
// 16KB/buf double-buffered = 32KB LDS -> 48KB LDS traffic per block-tile
// (writes 16 + reads 32), was 96-128KB. A prefetched one K-tile ahead into
// the alternate named register set (aA/aB, 2x unrolled loop - rule #20).
// Per iter: WAITV0 (A(t) regs + Bstage(t) landed; 12 loads issued iter t-1)
//   -> SBAR (all waves' Bstage(t)) -> 8 asm ds_read B -> issue Bstage(t+1)
//   into OTHER buf + 8 A-loads(t+1) -> LGKM0 -> 32 MFMA.
// Dbuf safety: stage(t+1) targets buf[(t+1)&1]; every wave's reads of that
// buf (iter t-1) retired before its LGKM0, which precedes its SBAR(t) join.
// T2 swizzle on B (verified R1-R10): row r chunk c at slot c^(r&7).
template <int DO_GELU>
__global__ __launch_bounds__(256, 3)
void gemm_tile_k(const ushort_t* __restrict__ A, const ushort_t* __restrict__ Bt,
                 const float* __restrict__ bias, void* __restrict__ Cout,
                 const int* __restrict__ rbe, const int* __restrict__ rbs,
                 int K, int N, int ncb) {
    int nwg = gridDim.x, bid = blockIdx.x;
    int wgid = (bid & 7) * (nwg >> 3) + (bid >> 3);  // XCD chunking (nwg%8==0)
    int rb = wgid / ncb, cb = wgid % ncb;
    int e = rbe[rb];
    if (e < 0) return;
    int slot0 = rbs[rb];

    __shared__ __align__(16) ushort_t lds[16384];   // 2 x 8192 (B dbuf, 32 KiB)

    int tid = threadIdx.x, lane = tid & 63, wid = tid >> 6;
    int wm = wid >> 1, wn = wid & 1;                 // 2M x 2N waves (64x64 each)
    int l15 = lane & 15, qh = lane >> 4, sw = l15 & 7;

    const ushort_t* Ab = A + (size_t)slot0 * K;
    const ushort_t* Bb = Bt + ((size_t)e * N + cb * 128) * K;

    // B staging: thread -> (row j 0..31, chunk q), source chunk pre-swizzled
    int j = tid >> 3, q = tid & 7;
    int cs = (q ^ (j & 7)) * 8;
    int ldsw = wid * 512;                            // wave-uniform dst in unit
    const ushort_t* bSrc = Bb + (size_t)j * K + cs;

    // B ds_read bases: row (=col of C) wn*64+n*16+l15, chunk XOR row swizzle
    int ch0 = (qh ^ sw) << 3;
    int ch1 = ((4 + qh) ^ sw) << 3;
    int bbase = (wn * 64 + l15) * 64;                // + n*1024 + chX

    // A-direct per-lane fragment pointers (advance 64 elems per K-tile)
    const ushort_t* ap[4];
#pragma unroll
    for (int m = 0; m < 4; ++m)
        ap[m] = Ab + (size_t)(wm * 64 + m * 16 + l15) * K + qh * 8;

#define STAGE_B(BUF, KT) do { \
    _Pragma("unroll") for (int u = 0; u < 4; ++u) \
        g2l16(bSrc + (size_t)u * 32 * K + (KT) * 64, &lds[(BUF) * 8192 + u * 2048 + ldsw]); \
} while (0)

#define LOADA(ARR) do { \
    _Pragma("unroll") for (int m = 0; m < 4; ++m) { \
        ARR[m * 2 + 0] = *(const bfx8*)(ap[m]); \
        ARR[m * 2 + 1] = *(const bfx8*)(ap[m] + 32); \
        ap[m] += 64; \
    } \
} while (0)

    fx4 acc[4][4];
#pragma unroll
    for (int m = 0; m < 4; ++m)
#pragma unroll
        for (int n = 0; n < 4; ++n) acc[m][n] = (fx4){0.f, 0.f, 0.f, 0.f};
    bfx8 aA[8], aB[8], b0v[4], b1v[4];

    int NT = K >> 6;   // 12 or 48 (even)
    STAGE_B(0, 0);
    LOADA(aA);

#define ITER(BUF, ACUR, ANEXT, TT) do { \
    WAITV0; \
    SBAR; \
    _Pragma("unroll") for (int n = 0; n < 4; ++n) \
        b0v[n] = dsr128((lus*)&lds[(BUF) * 8192 + bbase + n * 1024 + ch0]); \
    _Pragma("unroll") for (int n = 0; n < 4; ++n) \
        b1v[n] = dsr128((lus*)&lds[(BUF) * 8192 + bbase + n * 1024 + ch1]); \
    if ((TT) + 1 < NT) { \
        STAGE_B(1 - (BUF), (TT) + 1); \
        LOADA(ANEXT); \
    } \
    LGKM0; SCHED0; \
    PRIO1; \
    _Pragma("unroll") for (int m = 0; m < 4; ++m) \
    _Pragma("unroll") for (int n = 0; n < 4; ++n) \
        acc[m][n] = __builtin_amdgcn_mfma_f32_16x16x32_bf16(ACUR[m * 2 + 0], b0v[n], acc[m][n], 0, 0, 0); \
    _Pragma("unroll") for (int m = 0; m < 4; ++m) \
    _Pragma("unroll") for (int n = 0; n < 4; ++n) \
        acc[m][n] = __builtin_amdgcn_mfma_f32_16x16x32_bf16(ACUR[m * 2 + 1], b1v[n], acc[m][n], 0, 0, 0); \
    PRIO0; \
} while (0)

    for (int t = 0; t < NT; t += 2) {
        ITER(0, aA, aB, t);
        ITER(1, aB, aA, t + 1);
    }
#undef ITER
#undef LOADA
#undef STAGE_B

    // epilogue: C/D layout col=lane&15, row=(lane>>4)*4+reg (verified)
#pragma unroll
    for (int n = 0; n < 4; ++n) {
        int col = cb * 128 + wn * 64 + n * 16 + l15;
        float bvv = bias[(size_t)e * N + col];
#pragma unroll
        for (int m = 0; m < 4; ++m) {
            int rowb = slot0 + wm * 64 + m * 16 + qh * 4;
            fx4 v = acc[m][n];
#pragma unroll
            for (int jj = 0; jj < 4; ++jj) {
                float val = v[jj] + bvv;
                if (DO_GELU) {
                    ((ushort_t*)Cout)[(size_t)(rowb + jj) * N + col] = f2bf(gelu_tanh(val));
                } else {
                    ((float*)Cout)[(size_t)(rowb + jj) * N + col] = val;
                }
            }
        }
    }
}

// out[t] = w0 * y[slot0] + w1 * y[slot1]
__global__ void combine_k(const float* __restrict__ y, const int* __restrict__ aslot,
                          const float* __restrict__ twgt, float* __restrict__ out) {
    int i = blockIdx.x * 256 + threadIdx.x;   // T * (H/4)
    int t = i / (H / 4);
    int j = i % (H / 4);
    int s0 = aslot[t * 2], s1 = aslot[t * 2 + 1];
    float w0 = twgt[t * 2], w1 = twgt[t * 2 + 1];
    const float4 a = ((const float4*)(y + (size_t)s0 * H))[j];
    const float4 b = ((const float4*)(y + (size_t)s1 * H))[j];
    float4 r;
    r.x = w0 * a.x + w1 * b.x;
    r.y = w0 * a.y + w1 * b.y;
    r.z = w0 * a.z + w1 * b.z;
    r.w = w0 * a.w + w1 * b.w;
    ((float4*)(out + (size_t)t * H))[j] = r;
}

extern "C" void kernel_launch(void* const* d_in, const int* in_sizes, int n_in,
                              void* d_out, int out_size, void* d_ws, size_t ws_size,
                              hipStream_t stream) {
    const float* x  = (const float*)d_in[0];
    const float* gw = (const float*)d_in[1];
    const float* W1 = (const float*)d_in[2];
    const float* b1 = (const float*)d_in[3];
    const float* W2 = (const float*)d_in[4];
    const float* b2 = (const float*)d_in[5];
    float* out = (float*)d_out;

    char* ws = (char*)d_ws;
    size_t o = 0;
    auto carve = [&](size_t bytes) -> void* {
        o = (o + 255) & ~(size_t)255;
        void* p = ws + o;
        o += bytes;
        return p;
    };
    int*      tidx   = (int*)carve((size_t)NA * 4);
    float*    twgt   = (float*)carve((size_t)NA * 4);
    int*      counts = (int*)carve(NE * 4);
    int*      cursor = (int*)carve(NE * 4);
    int*      rbe    = (int*)carve(NRB * 4);
    int*      rbs    = (int*)carve(NRB * 4);
    int*      aslot  = (int*)carve((size_t)NA * 4);
    int*      tos    = (int*)carve((size_t)TP * 4);
    ushort_t* xg     = (ushort_t*)carve((size_t)TP * H * 2);
    ushort_t* w1t    = (ushort_t*)carve((size_t)NE * H * F * 2);
    ushort_t* w2t    = (ushort_t*)carve((size_t)NE * H * F * 2);
    ushort_t* hbuf   = (ushort_t*)carve((size_t)TP * F * 2);
    // ybuf overlays xg (+w1t head) — xg/w1t are dead once GEMM2 runs.
    float*    ybuf   = (float*)xg;
    (void)in_sizes; (void)n_in; (void)out_size; (void)ws_size;

    hipLaunchKernelGGL(init_k, dim3(TP / 256), dim3(256), 0, stream, counts, tos);
    hipLaunchKernelGGL(router_k, dim3(T / 4), dim3(256), 0, stream, x, gw, tidx, twgt);
    hipLaunchKernelGGL(count_k, dim3(NA / 256), dim3(256), 0, stream, tidx, counts);
    hipLaunchKernelGGL(offsets_k, dim3(1), dim3(1), 0, stream, counts, cursor, rbe, rbs);
    hipLaunchKernelGGL(scatter_k, dim3(NA / 256), dim3(256), 0, stream, tidx, cursor, tos, aslot);
    hipLaunchKernelGGL(gather_k, dim3(TP * (H / 8) / 256), dim3(256), 0, stream, x, tos, xg);
    hipLaunchKernelGGL(transpose_cast_k, dim3(F / 64, H / 64, NE), dim3(256), 0, stream, W1, w1t, H, F);
    hipLaunchKernelGGL(transpose_cast_k, dim3(H / 64, F / 64, NE), dim3(256), 0, stream, W2, w2t, F, H);
    // GEMM1: 128x128 tiles -> grid 72*24=1728
    hipLaunchKernelGGL((gemm_tile_k<1>), dim3(NRB * (F / 128)), dim3(256), 0, stream,
                       xg, w1t, b1, (void*)hbuf, rbe, rbs, H, F, F / 128);
    // GEMM2: 128x128 tiles -> grid 72*6=432
    hipLaunchKernelGGL((gemm_tile_k<0>), dim3(NRB * (H / 128)), dim3(256), 0, stream,
                       hbuf, w2t, b2, (void*)ybuf, rbe, rbs, F, H, H / 128);
    hipLaunchKernelGGL(combine_k, dim3(T * (H / 4) / 256), dim3(256), 0, stream,
                       ybuf, aslot, twgt, out);
}

// Round 12
// 256.336 us; speedup vs baseline: 1.9996x; 1.9996x over previous
//
#include <hip/hip_runtime.h>

#define H 768
#define F 3072
#define NE 8
#define T 4096
#define NA 8192      // T * K assignments
#define TP 9216      // padded slot capacity (128-aligned per expert)
#define NRB 72       // max 128-row blocks

typedef unsigned short ushort_t;
typedef __attribute__((ext_vector_type(8))) short bfx8;
typedef __attribute__((ext_vector_type(4))) float fx4;

__device__ __forceinline__ ushort_t f2bf(float f) {
    union { float f; unsigned u; } v; v.f = f;
    unsigned u = v.u;
    unsigned r = (u + 0x7fffu + ((u >> 16) & 1u)) >> 16;
    return (ushort_t)r;
}

__device__ __forceinline__ float gelu_tanh(float x) {
    const float c = 0.7978845608028654f;
    float z = c * (x + 0.044715f * x * x * x);
    float t = 1.0f - 2.0f / (__expf(2.0f * z) + 1.0f);   // tanh(z)
    return 0.5f * x * (1.0f + t);
}

__device__ __forceinline__ void g2l16(const void* g, void* l) {
    __builtin_amdgcn_global_load_lds(
        (__attribute__((address_space(1))) void*)g,
        (__attribute__((address_space(3))) void*)l, 16, 0, 0);
}

// ---------------- router: one wave per token ----------------
__global__ void router_k(const float* __restrict__ x, const float* __restrict__ gw,
                         int* __restrict__ tidx, float* __restrict__ twgt) {
    int t = blockIdx.x * 4 + (threadIdx.x >> 6);
    int lane = threadIdx.x & 63;
    const float* xr = x + (size_t)t * H;
    float acc[NE];
#pragma unroll
    for (int e = 0; e < NE; ++e) acc[e] = 0.f;
    for (int h = lane; h < H; h += 64) {
        float xv = xr[h];
        const float* g = gw + h * NE;
#pragma unroll
        for (int e = 0; e < NE; ++e) acc[e] += xv * g[e];
    }
#pragma unroll
    for (int off = 32; off > 0; off >>= 1) {
#pragma unroll
        for (int e = 0; e < NE; ++e) acc[e] += __shfl_down(acc[e], off);
    }
    if (lane == 0) {
        float l0 = -1e30f, l1 = -1e30f; int i0 = 0, i1 = 0;
#pragma unroll
        for (int e = 0; e < NE; ++e) {
            float v = acc[e];
            if (v > l0) { l1 = l0; i1 = i0; l0 = v; i0 = e; }
            else if (v > l1) { l1 = v; i1 = e; }
        }
        float w0 = 1.f / (1.f + __expf(l1 - l0));
        tidx[t * 2] = i0; tidx[t * 2 + 1] = i1;
        twgt[t * 2] = w0; twgt[t * 2 + 1] = 1.f - w0;
    }
}

__global__ void init_k(int* counts, int* tos) {
    int i = blockIdx.x * 256 + threadIdx.x;
    if (i < NE) counts[i] = 0;
    if (i < TP) tos[i] = -1;
}

__global__ void count_k(const int* __restrict__ tidx, int* counts) {
    int i = blockIdx.x * 256 + threadIdx.x;
    if (i < NA) atomicAdd(&counts[tidx[i]], 1);
}

__global__ void offsets_k(const int* __restrict__ counts, int* cursor,
                          int* rbe, int* rbs) {
    int off = 0, rb = 0;
    for (int e = 0; e < NE; ++e) {
        cursor[e] = off;
        int nrb = (counts[e] + 127) / 128;
        for (int j = 0; j < nrb; ++j) { rbe[rb] = e; rbs[rb] = off + j * 128; ++rb; }
        off += nrb * 128;
    }
    for (; rb < NRB; ++rb) rbe[rb] = -1;
}

__global__ void scatter_k(const int* __restrict__ tidx, int* cursor,
                          int* __restrict__ tos, int* __restrict__ aslot) {
    int i = blockIdx.x * 256 + threadIdx.x;
    if (i < NA) {
        int e = tidx[i];
        int slot = atomicAdd(&cursor[e], 1);
        tos[slot] = i >> 1;
        aslot[i] = slot;
    }
}

// gather selected token rows -> bf16, zeros for padding slots
__global__ void gather_k(const float* __restrict__ x, const int* __restrict__ tos,
                         ushort_t* __restrict__ xg) {
    int i = blockIdx.x * 256 + threadIdx.x;    // TP * (H/8)
    int slot = i / (H / 8);
    int j = i % (H / 8);
    int tok = tos[slot];
    ushort_t v[8];
    if (tok < 0) {
#pragma unroll
        for (int q = 0; q < 8; ++q) v[q] = 0;
    } else {
        const float* src = x + (size_t)tok * H + j * 8;
#pragma unroll
        for (int q = 0; q < 8; ++q) v[q] = f2bf(src[q]);
    }
    *(bfx8*)&xg[(size_t)slot * H + j * 8] = *(const bfx8*)v;
}

// fp32 [R][C] -> bf16 [C][R], per expert (blockIdx.z)
__global__ void transpose_cast_k(const float* __restrict__ src, ushort_t* __restrict__ dst,
                                 int R, int C) {
    int e = blockIdx.z;
    src += (size_t)e * R * C;
    dst += (size_t)e * R * C;
    int c0 = blockIdx.x * 64, r0 = blockIdx.y * 64;
    __shared__ float tile[64][65];
    int tid = threadIdx.x;
    int cc = tid & 63, rr = tid >> 6;    // rr 0..3
#pragma unroll
    for (int rep = 0; rep < 16; ++rep) {
        int r = rep * 4 + rr;
        tile[r][cc] = src[(size_t)(r0 + r) * C + c0 + cc];
    }
    __syncthreads();
#pragma unroll
    for (int rep = 0; rep < 16; ++rep) {
        int c = rep * 4 + rr;
        dst[(size_t)(c0 + c) * R + r0 + cc] = f2bf(tile[cc][c]);
    }
}

// ===== 128x128 x BK64 GEMM, 4 waves (wave tile 64x64), 1-stage LDS =====
// R12: m97 FAITHFUL replica — same addressing as R10 but the schedule is
// handed back to the compiler (Common-mistake #5 / m141: my asm ds_read +
// bulk LGKM + sched_barrier(0) pinned "all reads then all MFMAs", killing
// the fine-grained lgkmcnt read<->MFMA interleave hipcc emits for plain
// derefs — the documented 874-TF m97 structure). No asm barriers, no
// manual waitcnt, no setprio, no sched_barrier: STAGE -> __syncthreads()
// -> plain-deref reads + MFMA -> __syncthreads(). Cross-block overlap
// (3 blocks/CU, m114) hides the barrier vmcnt-drain.
// T2 swizzle (verified R1-R11): row r chunk c at slot c^(r&7), both sides.
template <int DO_GELU>
__global__ __launch_bounds__(256, 3)
void gemm_tile_k(const ushort_t* __restrict__ A, const ushort_t* __restrict__ Bt,
                 const float* __restrict__ bias, void* __restrict__ Cout,
                 const int* __restrict__ rbe, const int* __restrict__ rbs,
                 int K, int N, int ncb) {
    int nwg = gridDim.x, bid = blockIdx.x;
    int wgid = (bid & 7) * (nwg >> 3) + (bid >> 3);  // XCD chunking (nwg%8==0)
    int rb = wgid / ncb, cb = wgid % ncb;
    int e = rbe[rb];
    if (e < 0) return;
    int slot0 = rbs[rb];

    __shared__ __align__(16) ushort_t lds[16384];   // 32 KiB single buffer

    int tid = threadIdx.x, lane = tid & 63, wid = tid >> 6;
    int wm = wid >> 1, wn = wid & 1;                 // 2M x 2N waves
    int l15 = lane & 15, qh = lane >> 4, sw = l15 & 7;

    const ushort_t* Ab = A + (size_t)slot0 * K;
    const ushort_t* Bb = Bt + ((size_t)e * N + cb * 128) * K;

    // staging: thread -> (row j 0..31, chunk q), source chunk pre-swizzled
    int j = tid >> 3, q = tid & 7;
    int cs = (q ^ (j & 7)) * 8;
    int ldsw = wid * 512;                            // wave-uniform dst in unit
    const ushort_t* aSrc = Ab + (size_t)j * K + cs;
    const ushort_t* bSrc = Bb + (size_t)j * K + cs;

    // ds_read bases
    int ch0 = (qh ^ sw) << 3;
    int ch1 = ((4 + qh) ^ sw) << 3;
    int abase = (wm * 64 + l15) * 64;                // + m*1024 + chX
    int bbase = 8192 + (wn * 64 + l15) * 64;         // + n*1024 + chX

#define STAGE_T(KT) do { \
    _Pragma("unroll") for (int u = 0; u < 4; ++u) \
        g2l16(aSrc + (size_t)u * 32 * K + (KT) * 64, &lds[u * 2048 + ldsw]); \
    _Pragma("unroll") for (int u = 0; u < 4; ++u) \
        g2l16(bSrc + (size_t)u * 32 * K + (KT) * 64, &lds[8192 + u * 2048 + ldsw]); \
} while (0)

    fx4 acc[4][4];
#pragma unroll
    for (int m = 0; m < 4; ++m)
#pragma unroll
        for (int n = 0; n < 4; ++n) acc[m][n] = (fx4){0.f, 0.f, 0.f, 0.f};

    int NT = K >> 6;

    for (int t = 0; t < NT; ++t) {
        STAGE_T(t);
        __syncthreads();   // compiler drains vmcnt before barrier: tile ready
        bfx8 a0[4], a1[4], b0v[4], b1v[4];
#pragma unroll
        for (int m = 0; m < 4; ++m) a0[m] = *(const bfx8*)&lds[abase + m * 1024 + ch0];
#pragma unroll
        for (int n = 0; n < 4; ++n) b0v[n] = *(const bfx8*)&lds[bbase + n * 1024 + ch0];
#pragma unroll
        for (int m = 0; m < 4; ++m) a1[m] = *(const bfx8*)&lds[abase + m * 1024 + ch1];
#pragma unroll
        for (int n = 0; n < 4; ++n) b1v[n] = *(const bfx8*)&lds[bbase + n * 1024 + ch1];
#pragma unroll
        for (int m = 0; m < 4; ++m)
#pragma unroll
            for (int n = 0; n < 4; ++n)
                acc[m][n] = __builtin_amdgcn_mfma_f32_16x16x32_bf16(a0[m], b0v[n], acc[m][n], 0, 0, 0);
#pragma unroll
        for (int m = 0; m < 4; ++m)
#pragma unroll
            for (int n = 0; n < 4; ++n)
                acc[m][n] = __builtin_amdgcn_mfma_f32_16x16x32_bf16(a1[m], b1v[n], acc[m][n], 0, 0, 0);
        __syncthreads();   // all reads retired before next stage overwrites
    }
#undef STAGE_T

    // epilogue: C/D layout col=lane&15, row=(lane>>4)*4+reg (verified)
#pragma unroll
    for (int n = 0; n < 4; ++n) {
        int col = cb * 128 + wn * 64 + n * 16 + l15;
        float bvv = bias[(size_t)e * N + col];
#pragma unroll
        for (int m = 0; m < 4; ++m) {
            int rowb = slot0 + wm * 64 + m * 16 + qh * 4;
            fx4 v = acc[m][n];
#pragma unroll
            for (int jj = 0; jj < 4; ++jj) {
                float val = v[jj] + bvv;
                if (DO_GELU) {
                    ((ushort_t*)Cout)[(size_t)(rowb + jj) * N + col] = f2bf(gelu_tanh(val));
                } else {
                    ((float*)Cout)[(size_t)(rowb + jj) * N + col] = val;
                }
            }
        }
    }
}

// out[t] = w0 * y[slot0] + w1 * y[slot1]
__global__ void combine_k(const float* __restrict__ y, const int* __restrict__ aslot,
                          const float* __restrict__ twgt, float* __restrict__ out) {
    int i = blockIdx.x * 256 + threadIdx.x;   // T * (H/4)
    int t = i / (H / 4);
    int j = i % (H / 4);
    int s0 = aslot[t * 2], s1 = aslot[t * 2 + 1];
    float w0 = twgt[t * 2], w1 = twgt[t * 2 + 1];
    const float4 a = ((const float4*)(y + (size_t)s0 * H))[j];
    const float4 b = ((const float4*)(y + (size_t)s1 * H))[j];
    float4 r;
    r.x = w0 * a.x + w1 * b.x;
    r.y = w0 * a.y + w1 * b.y;
    r.z = w0 * a.z + w1 * b.z;
    r.w = w0 * a.w + w1 * b.w;
    ((float4*)(out + (size_t)t * H))[j] = r;
}

extern "C" void kernel_launch(void* const* d_in, const int* in_sizes, int n_in,
                              void* d_out, int out_size, void* d_ws, size_t ws_size,
                              hipStream_t stream) {
    const float* x  = (const float*)d_in[0];
    const float* gw = (const float*)d_in[1];
    const float* W1 = (const float*)d_in[2];
    const float* b1 = (const float*)d_in[3];
    const float* W2 = (const float*)d_in[4];
    const float* b2 = (const float*)d_in[5];
    float* out = (float*)d_out;

    char* ws = (char*)d_ws;
    size_t o = 0;
    auto carve = [&](size_t bytes) -> void* {
        o = (o + 255) & ~(size_t)255;
        void* p = ws + o;
        o += bytes;
        return p;
    };
    int*      tidx   = (int*)carve((size_t)NA * 4);
    float*    twgt   = (float*)carve((size_t)NA * 4);
    int*      counts = (int*)carve(NE * 4);
    int*      cursor = (int*)carve(NE * 4);
    int*      rbe    = (int*)carve(NRB * 4);
    int*      rbs    = (int*)carve(NRB * 4);
    int*      aslot  = (int*)carve((size_t)NA * 4);
    int*      tos    = (int*)carve((size_t)TP * 4);
    ushort_t* xg     = (ushort_t*)carve((size_t)TP * H * 2);
    ushort_t* w1t    = (ushort_t*)carve((size_t)NE * H * F * 2);
    ushort_t* w2t    = (ushort_t*)carve((size_t)NE * H * F * 2);
    ushort_t* hbuf   = (ushort_t*)carve((size_t)TP * F * 2);
    // ybuf overlays xg (+w1t head) — xg/w1t are dead once GEMM2 runs.
    float*    ybuf   = (float*)xg;
    (void)in_sizes; (void)n_in; (void)out_size; (void)ws_size;

    hipLaunchKernelGGL(init_k, dim3(TP / 256), dim3(256), 0, stream, counts, tos);
    hipLaunchKernelGGL(router_k, dim3(T / 4), dim3(256), 0, stream, x, gw, tidx, twgt);
    hipLaunchKernelGGL(count_k, dim3(NA / 256), dim3(256), 0, stream, tidx, counts);
    hipLaunchKernelGGL(offsets_k, dim3(1), dim3(1), 0, stream, counts, cursor, rbe, rbs);
    hipLaunchKernelGGL(scatter_k, dim3(NA / 256), dim3(256), 0, stream, tidx, cursor, tos, aslot);
    hipLaunchKernelGGL(gather_k, dim3(TP * (H / 8) / 256), dim3(256), 0, stream, x, tos, xg);
    hipLaunchKernelGGL(transpose_cast_k, dim3(F / 64, H / 64, NE), dim3(256), 0, stream, W1, w1t, H, F);
    hipLaunchKernelGGL(transpose_cast_k, dim3(H / 64, F / 64, NE), dim3(256), 0, stream, W2, w2t, F, H);
    // GEMM1: 128x128 tiles -> grid 72*24=1728 (~2.25 rounds at 3 blocks/CU)
    hipLaunchKernelGGL((gemm_tile_k<1>), dim3(NRB * (F / 128)), dim3(256), 0, stream,
                       xg, w1t, b1, (void*)hbuf, rbe, rbs, H, F, F / 128);
    // GEMM2: 128x128 tiles -> grid 72*6=432
    hipLaunchKernelGGL((gemm_tile_k<0>), dim3(NRB * (H / 128)), dim3(256), 0, stream,
                       hbuf, w2t, b2, (void*)ybuf, rbe, rbs, F, H, H / 128);
    hipLaunchKernelGGL(combine_k, dim3(T * (H / 4) / 256), dim3(256), 0, stream,
                       ybuf, aslot, twgt, out);
}